// Round 4
// baseline (258.610 us; speedup 1.0000x reference)
//
#include <hip/hip_runtime.h>

#define BB   8
#define CC   1024
#define NN   4096
#define KL   32
#define KK   1024
#define XMINF (-15.0f)
#define SPANF 30.0f
#define EPSF  1e-6f
#define WS_SCALE  33554432.0f      // 2^25 fixed point for weight sums
#define WS_INV    (1.0f/33554432.0f)
#define WQ_MAX    1048575.0f       // 20-bit normalized-weight quantization
#define WQ_INV    (1.0f/1048575.0f)
#define OFFS_STRIDE 1028           // 16B-aligned per-batch offset stride

__device__ __forceinline__ unsigned bf16rne(float x) {
  unsigned u = __float_as_uint(x);
  return (u + 0x7fffu + ((u >> 16) & 1u)) >> 16;
}
__device__ __forceinline__ unsigned pk2(float lo, float hi) {
  return bf16rne(lo) | (bf16rne(hi) << 16);
}

// ---------------- Phase 1: cell-CSR build + weights output ------------------
// One block per batch. Each pixel emits 4 entries (one per bilinear neighbor
// cell), weight pre-normalized by that cell's wsum and quantized to 20 bits.
// Entry = pix:12 | wnorm_q:20. All atomics are native u32 LDS atomics.
__global__ __launch_bounds__(256) void WLP_build_kernel(
    const float2* __restrict__ coord,      // (B, N)
    unsigned*     __restrict__ entries_g,  // (B, 4*N)
    unsigned*     __restrict__ offs_g,     // (B, OFFS_STRIDE)
    float*        __restrict__ weights_out)// (B, 16, KK)
{
  const int b = blockIdx.x, tid = threadIdx.x;
  __shared__ unsigned cnt[KK];    // entry counts, then CSR cursor
  __shared__ unsigned offl[KK];   // CSR offsets
  __shared__ unsigned wsl[KK];    // fixed-point wsum, then bitcast inv-scale
  __shared__ unsigned wave_tot[4];
  for (int i = tid; i < KK; i += 256) { cnt[i] = 0u; wsl[i] = 0u; }
  __syncthreads();

  unsigned pk[16];
  #pragma unroll
  for (int it = 0; it < 16; ++it) {
    int n = it * 256 + tid;
    float2 c = coord[(b << 12) + n];
    float gx = (c.x - XMINF) * (31.0f / SPANF);
    float gy = (c.y - XMINF) * (31.0f / SPANF);
    int cx = (int)floorf(gx); cx = min(max(cx, 0), 30);
    int cy = (int)floorf(gy); cy = min(max(cy, 0), 30);
    float wx = gx - (float)cx, wy = gy - (float)cy;
    int qx = __float2int_rn(wx * 1023.0f); qx = min(max(qx, 0), 1023);
    int qy = __float2int_rn(wy * 1023.0f); qy = min(max(qy, 0), 1023);
    unsigned bu = (unsigned)(cy * KL + cx);
    pk[it] = bu | ((unsigned)qx << 10) | ((unsigned)qy << 20);
    atomicAdd(&cnt[bu], 1u);      atomicAdd(&cnt[bu + 1], 1u);
    atomicAdd(&cnt[bu + KL], 1u); atomicAdd(&cnt[bu + KL + 1], 1u);
    float dx = (float)qx * (1.0f/1023.0f), dy = (float)qy * (1.0f/1023.0f);
    float ex = 1.0f - dx, ey = 1.0f - dy;
    atomicAdd(&wsl[bu],         (unsigned)__float2int_rn(ex*ey*WS_SCALE));
    atomicAdd(&wsl[bu+1],       (unsigned)__float2int_rn(dx*ey*WS_SCALE));
    atomicAdd(&wsl[bu+KL],      (unsigned)__float2int_rn(ex*dy*WS_SCALE));
    atomicAdd(&wsl[bu+KL+1],    (unsigned)__float2int_rn(dx*dy*WS_SCALE));
  }
  __syncthreads();

  // exclusive scan of cnt[1024] -> offl[1024]
  uint4 c4 = ((const uint4*)cnt)[tid];
  unsigned tsum = c4.x + c4.y + c4.z + c4.w;
  int lane = tid & 63, wid = tid >> 6;
  unsigned v = tsum;
  #pragma unroll
  for (int d = 1; d < 64; d <<= 1) { unsigned u = __shfl_up(v, d, 64); if (lane >= d) v += u; }
  if (lane == 63) wave_tot[wid] = v;
  unsigned wexcl = v - tsum;
  __syncthreads();
  unsigned base = wexcl;
  for (int w = 0; w < wid; ++w) base += wave_tot[w];
  offl[4*tid]   = base;
  offl[4*tid+1] = base + c4.x;
  offl[4*tid+2] = base + c4.x + c4.y;
  offl[4*tid+3] = base + c4.x + c4.y + c4.z;
  __syncthreads();

  #pragma unroll
  for (int i = 0; i < 4; ++i) offs_g[b * OFFS_STRIDE + 4*tid + i] = offl[4*tid + i];
  if (tid == 0) offs_g[b * OFFS_STRIDE + 1024] = 4u * NN;

  // cursor = CSR offsets; weights output; wsl -> bitcast inverse scale
  for (int i = tid; i < KK; i += 256) {
    cnt[i] = offl[i];
    float s = (float)wsl[i] * WS_INV;
    #pragma unroll
    for (int t = 0; t < 16; ++t)
      weights_out[((size_t)(b * 16 + t) << 10) + i] = s;
    wsl[i] = __float_as_uint(WQ_MAX / fmaxf(s, EPSF));
  }
  __syncthreads();

  // pass B: emit 4 entries per pixel with pre-normalized quantized weights
  #pragma unroll
  for (int it = 0; it < 16; ++it) {
    unsigned n = (unsigned)(it * 256 + tid);
    unsigned u = pk[it];
    unsigned bu = u & 1023u;
    float dx = (float)((u >> 10) & 1023u) * (1.0f/1023.0f);
    float dy = (float)((u >> 20) & 1023u) * (1.0f/1023.0f);
    float ex = 1.0f - dx, ey = 1.0f - dy;
    #define EMIT(cell, wv) { \
      unsigned cl = (cell); \
      float q = (wv) * __uint_as_float(wsl[cl]); \
      unsigned wq = (unsigned)__float2int_rn(fminf(q, WQ_MAX)); \
      unsigned slot = atomicAdd(&cnt[cl], 1u); \
      entries_g[(b << 14) + slot] = n | (wq << 12); }
    EMIT(bu,          ex * ey)
    EMIT(bu + 1,      dx * ey)
    EMIT(bu + KL,     ex * dy)
    EMIT(bu + KL + 1, dx * dy)
    #undef EMIT
  }
}

// ---------------- Phase 2: per-(b, channel-pair) CSR gather ------------------
// No atomics. Rows staged as bf16x2 (both channels in one u32). Thread tid
// owns cells 4tid..4tid+3 (contiguous CSR ranges), accumulates in registers,
// writes two coalesced float4 stores.
__global__ __launch_bounds__(256, 8) void WLP_gather_kernel(
    const float*    __restrict__ feats,      // (B, CC, NN)
    const unsigned* __restrict__ entries_g,  // (B, 4*N)
    const unsigned* __restrict__ offs_g,     // (B, OFFS_STRIDE)
    float*          __restrict__ world)      // (B, CC, KK)
{
  const int bg  = blockIdx.x;          // b * 512 + pair
  const int b   = bg >> 9;
  const int c0  = (bg & 511) << 1;
  const int tid = threadIdx.x;

  __shared__ unsigned rows[NN];        // 16 KB: [pix] = bf16(c0) | bf16(c1)<<16

  const float4* f0 = (const float4*)(feats + (((size_t)(b << 10) + c0) << 12));
  const float4* f1 = f0 + (NN / 4);
  #pragma unroll
  for (int k = 0; k < 4; ++k) {
    int p4 = k * 256 + tid;
    float4 a = f0[p4], c = f1[p4];
    uint4 o;
    o.x = pk2(a.x, c.x); o.y = pk2(a.y, c.y);
    o.z = pk2(a.z, c.z); o.w = pk2(a.w, c.w);
    ((uint4*)rows)[p4] = o;
  }
  const unsigned* ofs = offs_g + b * OFFS_STRIDE + (tid << 2);
  uint4 o4 = *(const uint4*)ofs;      // offsets for cells 4tid..4tid+3
  unsigned oend = ofs[4];
  __syncthreads();

  const unsigned* eb = entries_g + (b << 14);
  unsigned beg[4] = {o4.x, o4.y, o4.z, o4.w};
  unsigned end[4] = {o4.y, o4.z, o4.w, oend};
  float accA[4], accB[4];
  #pragma unroll
  for (int cc = 0; cc < 4; ++cc) {
    float a0 = 0.f, a1 = 0.f;
    for (unsigned i = beg[cc]; i < end[cc]; ++i) {
      unsigned u  = eb[i];
      float    wq = (float)(u >> 12);
      unsigned vv = rows[u & 4095u];
      float g0 = __uint_as_float(vv << 16);
      float g1 = __uint_as_float(vv & 0xffff0000u);
      a0 = fmaf(wq, g0, a0);
      a1 = fmaf(wq, g1, a1);
    }
    accA[cc] = a0 * WQ_INV;
    accB[cc] = a1 * WQ_INV;
  }
  const size_t ob = ((size_t)(b << 10) + c0) << 10;
  *(float4*)(world + ob + (tid << 2)) =
      make_float4(accA[0], accA[1], accA[2], accA[3]);
  *(float4*)(world + ob + KK + (tid << 2)) =
      make_float4(accB[0], accB[1], accB[2], accB[3]);
}

extern "C" void kernel_launch(void* const* d_in, const int* in_sizes, int n_in,
                              void* d_out, int out_size, void* d_ws, size_t ws_size,
                              hipStream_t stream) {
  const float*  feats = (const float*)d_in[0];   // (B,T,D,HP,WP) = (B,1024,4096)
  const float2* coord = (const float2*)d_in[1];  // (B,HP,WP) float2
  float* out = (float*)d_out;
  float* world       = out;                          // B*CC*KK
  float* weights_out = out + (size_t)BB * CC * KK;   // B*16*KK

  unsigned* entries_g = (unsigned*)d_ws;                 // 8 * 16384 u32 (512 KB)
  unsigned* offs_g    = entries_g + BB * 4 * NN;         // 8 * 1028 u32

  WLP_build_kernel<<<BB, 256, 0, stream>>>(coord, entries_g, offs_g, weights_out);
  WLP_gather_kernel<<<BB * CC / 2, 256, 0, stream>>>(feats, entries_g, offs_g, world);
}

// Round 5
// 55.726 us; speedup vs baseline: 4.6407x; 4.6407x over previous
//
#include <hip/hip_runtime.h>

#define BB   8
#define CC   1024
#define NN   4096
#define KL   32
#define KK   1024
#define XMINF (-15.0f)
#define SPANF 30.0f
#define EPSF  1e-6f
#define ACC_SCALE 1048576.0f       // 2^20 fixed point for feature accum
#define ACC_INV   (1.0f/1048576.0f)
#define WS_SCALE  33554432.0f      // 2^25 fixed point for weight sums
#define WS_INV    (1.0f/33554432.0f)

// round-half-up bf16x2 pack: low16 = bf16(lo), high16 = bf16(hi)
__device__ __forceinline__ unsigned pkru(float lo, float hi) {
  unsigned ul = __float_as_uint(lo), uh = __float_as_uint(hi);
  return ((ul + 0x8000u) >> 16) | ((uh + 0x8000u) & 0xffff0000u);
}

// ---------------- Phase 1: bucket/CSR build + wsum + weights output ----------
// (verbatim round-2 build: proven correct, ~5us)
__global__ __launch_bounds__(256) void WLP_build_kernel(
    const float2*   __restrict__ coord,      // (B, N)
    unsigned*       __restrict__ entries_g,  // (B, N) packed pix|qx|qy
    unsigned*       __restrict__ offs_g,     // (B, 1025)
    unsigned short* __restrict__ startbid_g, // (B, 256)
    float*          __restrict__ wsum_g,     // (B, KK)
    float*          __restrict__ weights_out)// (B, 16, KK)
{
  const int b = blockIdx.x, tid = threadIdx.x;
  __shared__ unsigned cnt[KK];
  __shared__ unsigned offl[KK];
  __shared__ unsigned wsl[KK];
  __shared__ unsigned wave_tot[4];
  for (int i = tid; i < KK; i += 256) { cnt[i] = 0u; wsl[i] = 0u; }
  __syncthreads();

  unsigned bkt[16]; unsigned pk[16];
  #pragma unroll
  for (int it = 0; it < 16; ++it) {
    int n = it * 256 + tid;
    float2 c = coord[(b << 12) + n];
    float gx = (c.x - XMINF) * (31.0f / SPANF);
    float gy = (c.y - XMINF) * (31.0f / SPANF);
    int cx = (int)floorf(gx); cx = min(max(cx, 0), 30);
    int cy = (int)floorf(gy); cy = min(max(cy, 0), 30);
    float wx = gx - (float)cx, wy = gy - (float)cy;
    int qx = __float2int_rn(wx * 1023.0f); qx = min(max(qx, 0), 1023);
    int qy = __float2int_rn(wy * 1023.0f); qy = min(max(qy, 0), 1023);
    unsigned bu = (unsigned)(cy * KL + cx);
    bkt[it] = bu;
    pk[it]  = (unsigned)n | ((unsigned)qx << 12) | ((unsigned)qy << 22);
    atomicAdd(&cnt[bu], 1u);
    float dx = (float)qx * (1.0f/1023.0f), dy = (float)qy * (1.0f/1023.0f);
    float ex = 1.0f - dx, ey = 1.0f - dy;
    atomicAdd(&wsl[bu],          (unsigned)__float2int_rn(ex*ey*WS_SCALE));
    atomicAdd(&wsl[bu+1],        (unsigned)__float2int_rn(dx*ey*WS_SCALE));
    atomicAdd(&wsl[bu+KL],       (unsigned)__float2int_rn(ex*dy*WS_SCALE));
    atomicAdd(&wsl[bu+KL+1],     (unsigned)__float2int_rn(dx*dy*WS_SCALE));
  }
  __syncthreads();

  // exclusive scan of cnt[1024] -> offl[1024]
  uint4 c4 = ((const uint4*)cnt)[tid];
  unsigned tsum = c4.x + c4.y + c4.z + c4.w;
  int lane = tid & 63, wid = tid >> 6;
  unsigned v = tsum;
  #pragma unroll
  for (int d = 1; d < 64; d <<= 1) { unsigned u = __shfl_up(v, d, 64); if (lane >= d) v += u; }
  if (lane == 63) wave_tot[wid] = v;
  unsigned wexcl = v - tsum;
  __syncthreads();
  unsigned base = wexcl;
  for (int w = 0; w < wid; ++w) base += wave_tot[w];
  offl[4*tid]   = base;
  offl[4*tid+1] = base + c4.x;
  offl[4*tid+2] = base + c4.x + c4.y;
  offl[4*tid+3] = base + c4.x + c4.y + c4.z;
  __syncthreads();

  #pragma unroll
  for (int i = 0; i < 4; ++i) offs_g[b*1025 + 4*tid + i] = offl[4*tid + i];
  if (tid == 0) offs_g[b*1025 + 1024] = NN;

  // per-thread start bucket for phase 2 (entry range [16*tid, 16*tid+16))
  {
    int target = tid * 16, bid = 0;
    #pragma unroll
    for (int s = 512; s > 0; s >>= 1) {
      int cand = bid + s;
      if (cand <= 1023 && (int)offl[cand] <= target) bid = cand;
    }
    startbid_g[(b << 8) + tid] = (unsigned short)bid;
  }

  // cursor = copy of offsets (cnt reused), then scatter entries into slots
  for (int i = tid; i < KK; i += 256) cnt[i] = offl[i];
  __syncthreads();
  #pragma unroll
  for (int it = 0; it < 16; ++it) {
    unsigned slot = atomicAdd(&cnt[bkt[it]], 1u);
    entries_g[(b << 12) + slot] = pk[it];
  }

  // wsum + broadcast weights output
  for (int i = tid; i < KK; i += 256) {
    float s = (float)wsl[i] * WS_INV;
    wsum_g[(b << 10) + i] = s;
    #pragma unroll
    for (int t = 0; t < 16; ++t)
      weights_out[((size_t)(b * 16 + t) << 10) + i] = s;
  }
}

// ---------------- Phase 2: per-(b, channel-pair) scatter ---------------------
// Round-2 structure (coalesced uint4 entry loads, register run-accumulation,
// u32 fixed-point LDS atomic flush) with G=2 channels: rows packed bf16x2 in
// one u32 so a single ds_read_b32 serves both channels. LDS = 26 KB -> 6
// blocks/CU.
__global__ __launch_bounds__(256, 6) void WLP_gather_kernel(
    const float*          __restrict__ feats,      // (B, CC, NN)
    const unsigned*       __restrict__ entries_g,
    const unsigned*       __restrict__ offs_g,
    const unsigned short* __restrict__ startbid_g,
    const float*          __restrict__ wsum_g,
    float*                __restrict__ world)      // (B, CC, KK)
{
  const int bg  = blockIdx.x;          // b * 512 + pair
  const int b   = bg >> 9;
  const int c0  = (bg & 511) << 1;
  const int tid = threadIdx.x;

  __shared__ unsigned       rows[NN];        // 16 KB: bf16(c0) | bf16(c1)<<16
  __shared__ unsigned short off_l[KK + 2];   // 2 KB
  __shared__ int            acc[2 * KK];     // [ch][cell] 8 KB

  // stage both rows packed (coalesced b128 in/out)
  const float4* f0 = (const float4*)(feats + (((size_t)(b << 10) + c0) << 12));
  const float4* f1 = f0 + (NN / 4);
  #pragma unroll
  for (int k = 0; k < 4; ++k) {
    int p4 = k * 256 + tid;
    float4 a = f0[p4], c = f1[p4];
    uint4 o;
    o.x = pkru(a.x, c.x); o.y = pkru(a.y, c.y);
    o.z = pkru(a.z, c.z); o.w = pkru(a.w, c.w);
    ((uint4*)rows)[p4] = o;
  }
  for (int i = tid; i < KK + 1; i += 256) off_l[i] = (unsigned short)offs_g[b * 1025 + i];
  #pragma unroll
  for (int k = 0; k < 8; ++k) acc[k * 256 + tid] = 0;

  const uint4* eb = (const uint4*)(entries_g + (b << 12));
  uint4 e0 = eb[4*tid], e1 = eb[4*tid+1], e2v = eb[4*tid+2], e3 = eb[4*tid+3];
  int bid = startbid_g[(b << 8) + tid];
  __syncthreads();

  int nxt = off_l[bid + 1];
  float a00=0.f, a10=0.f, a01=0.f, a11=0.f;   // channel c0
  float c00=0.f, c10=0.f, c01=0.f, c11=0.f;   // channel c0+1
  bool dirty = false;
  int e = tid * 16;

  #define FLUSH() { \
    atomicAdd(&acc[bid],           (int)__float2int_rn(a00 * ACC_SCALE)); \
    atomicAdd(&acc[bid+1],         (int)__float2int_rn(a10 * ACC_SCALE)); \
    atomicAdd(&acc[bid+KL],        (int)__float2int_rn(a01 * ACC_SCALE)); \
    atomicAdd(&acc[bid+KL+1],      (int)__float2int_rn(a11 * ACC_SCALE)); \
    atomicAdd(&acc[KK+bid],        (int)__float2int_rn(c00 * ACC_SCALE)); \
    atomicAdd(&acc[KK+bid+1],      (int)__float2int_rn(c10 * ACC_SCALE)); \
    atomicAdd(&acc[KK+bid+KL],     (int)__float2int_rn(c01 * ACC_SCALE)); \
    atomicAdd(&acc[KK+bid+KL+1],   (int)__float2int_rn(c11 * ACC_SCALE)); \
    a00=a10=a01=a11=0.f; c00=c10=c01=c11=0.f; dirty = false; }

  #define PROC(u) { \
    while (e >= nxt) { if (dirty) FLUSH(); ++bid; nxt = off_l[bid + 1]; } \
    float fx = (float)((u >> 12) & 1023u) * (1.0f/1023.0f); \
    float fy = (float)(u >> 22) * (1.0f/1023.0f); \
    unsigned vv = rows[u & 4095u]; \
    float ex = 1.0f - fx, ey = 1.0f - fy; \
    float w00 = ex*ey, w10 = fx*ey, w01 = ex*fy, w11 = fx*fy; \
    float g0 = __uint_as_float(vv << 16); \
    float g1 = __uint_as_float(vv & 0xffff0000u); \
    a00 = fmaf(w00,g0,a00); a10 = fmaf(w10,g0,a10); \
    a01 = fmaf(w01,g0,a01); a11 = fmaf(w11,g0,a11); \
    c00 = fmaf(w00,g1,c00); c10 = fmaf(w10,g1,c10); \
    c01 = fmaf(w01,g1,c01); c11 = fmaf(w11,g1,c11); \
    dirty = true; ++e; }

  PROC(e0.x) PROC(e0.y) PROC(e0.z) PROC(e0.w)
  PROC(e1.x) PROC(e1.y) PROC(e1.z) PROC(e1.w)
  PROC(e2v.x) PROC(e2v.y) PROC(e2v.z) PROC(e2v.w)
  PROC(e3.x) PROC(e3.y) PROC(e3.z) PROC(e3.w)
  if (dirty) FLUSH();
  #undef PROC
  #undef FLUSH
  __syncthreads();

  // epilogue: thread owns cells 4t..4t+3; one divide per cell, shared by pair
  const size_t ob = ((size_t)(b << 10) + c0) << 10;
  int4   ia = ((const int4*)acc)[tid];
  int4   ib = ((const int4*)(acc + KK))[tid];
  float4 w4 = ((const float4*)(wsum_g + (b << 10)))[tid];
  float i0 = ACC_INV / fmaxf(w4.x, EPSF);
  float i1 = ACC_INV / fmaxf(w4.y, EPSF);
  float i2 = ACC_INV / fmaxf(w4.z, EPSF);
  float i3 = ACC_INV / fmaxf(w4.w, EPSF);
  *(float4*)(world + ob + (tid << 2)) =
      make_float4((float)ia.x * i0, (float)ia.y * i1, (float)ia.z * i2, (float)ia.w * i3);
  *(float4*)(world + ob + KK + (tid << 2)) =
      make_float4((float)ib.x * i0, (float)ib.y * i1, (float)ib.z * i2, (float)ib.w * i3);
}

extern "C" void kernel_launch(void* const* d_in, const int* in_sizes, int n_in,
                              void* d_out, int out_size, void* d_ws, size_t ws_size,
                              hipStream_t stream) {
  const float*  feats = (const float*)d_in[0];   // (B,T,D,HP,WP) = (B,1024,4096)
  const float2* coord = (const float2*)d_in[1];  // (B,HP,WP) float2
  float* out = (float*)d_out;
  float* world       = out;                          // B*CC*KK
  float* weights_out = out + (size_t)BB * CC * KK;   // B*16*KK

  unsigned*       entries_g  = (unsigned*)d_ws;                       // 8*4096 u32
  unsigned*       offs_g     = entries_g + BB * NN;                   // 8*1025 u32
  float*          wsum_g     = (float*)(offs_g + BB * 1025);          // 8*1024 f32
  unsigned short* startbid_g = (unsigned short*)(wsum_g + BB * KK);   // 8*256 u16

  WLP_build_kernel<<<BB, 256, 0, stream>>>(coord, entries_g, offs_g, startbid_g,
                                           wsum_g, weights_out);
  WLP_gather_kernel<<<BB * CC / 2, 256, 0, stream>>>(feats, entries_g, offs_g,
                                                     startbid_g, wsum_g, world);
}

// Round 7
// 51.074 us; speedup vs baseline: 5.0634x; 1.0911x over previous
//
#include <hip/hip_runtime.h>

#define BB   8
#define CC   1024
#define NN   4096
#define KL   32
#define KK   1024
#define XMINF (-15.0f)
#define EPSF  1e-6f
#define ACC_SCALE 4194304.0f       // 2^22 fixed point for feature accum
#define ACC_INV   (1.0f/4194304.0f)
#define WS_SCALE  33554432.0f      // 2^25 fixed point for weight sums
#define WS_INV    (1.0f/33554432.0f)

// Single fused kernel: one block per (batch, channel-pair). No workspace, no
// inter-kernel dependencies, no cross-block communication — every block
// computes everything it needs from the (read-only) inputs, so the output is
// a pure function of d_in on every call (integer atomics => order-independent).
//
// Per block: recompute the coord->lattice transform for all 4096 pixels
// (cheap VALU, amortized over 2 channels), accumulate wsum (2^25 fixed point)
// and both channels' cell sums (2^22 fixed point) via native u32/int LDS
// atomics, then normalize and store. LDS = 12.25 KB -> 8 blocks/CU, 100%
// wave occupancy. Feats read directly as coalesced float4 (fp32 precision).
__global__ __launch_bounds__(256, 8) void WLP_fused_kernel(
    const float*  __restrict__ feats,      // (B, CC, NN)
    const float2* __restrict__ coord,      // (B, N)
    float*        __restrict__ world,      // (B, CC, KK)
    float*        __restrict__ weights_out)// (B, 16, KK)
{
  const int bg  = blockIdx.x;          // b * 512 + pair
  const int b   = bg >> 9;
  const int pr  = bg & 511;
  const int c0  = pr << 1;
  const int tid = threadIdx.x;

  __shared__ int      acc[2 * KK];     // [ch][cell], 8 KB, 2^22 fixed point
  __shared__ unsigned wsl[KK];         // 4 KB, 2^25 fixed point
  ((int4*)acc)[tid]       = make_int4(0, 0, 0, 0);
  ((int4*)acc)[256 + tid] = make_int4(0, 0, 0, 0);
  ((uint4*)wsl)[tid]      = make_uint4(0, 0, 0, 0);
  __syncthreads();

  const float4* f0 = (const float4*)(feats + (((size_t)(b << 10) | c0) << 12));
  const float4* f1 = f0 + (NN / 4);
  const float4* cm = (const float4*)(coord + (b << 12));  // 2 pixels / float4

  for (int it = 0; it < 4; ++it) {
    int q = it * 256 + tid;            // pixel-quad index
    float4 cA = cm[2 * q];             // pixels 4q, 4q+1
    float4 cB = cm[2 * q + 1];         // pixels 4q+2, 4q+3
    float4 a  = f0[q];                 // channel c0
    float4 c  = f1[q];                 // channel c0+1
    #define SPLAT(px, py, fa, fc) { \
      float gx = ((px) - XMINF) * (31.0f / 30.0f); \
      float gy = ((py) - XMINF) * (31.0f / 30.0f); \
      int cx = min(max((int)floorf(gx), 0), 30); \
      int cy = min(max((int)floorf(gy), 0), 30); \
      float wx = gx - (float)cx, wy = gy - (float)cy; \
      float ex = 1.0f - wx,      ey = 1.0f - wy; \
      float w00 = ex*ey, w10 = wx*ey, w01 = ex*wy, w11 = wx*wy; \
      int bu = cy * KL + cx; \
      atomicAdd(&wsl[bu],        (unsigned)__float2int_rn(w00 * WS_SCALE)); \
      atomicAdd(&wsl[bu+1],      (unsigned)__float2int_rn(w10 * WS_SCALE)); \
      atomicAdd(&wsl[bu+KL],     (unsigned)__float2int_rn(w01 * WS_SCALE)); \
      atomicAdd(&wsl[bu+KL+1],   (unsigned)__float2int_rn(w11 * WS_SCALE)); \
      float s0 = (fa) * ACC_SCALE, s1 = (fc) * ACC_SCALE; \
      atomicAdd(&acc[bu],          __float2int_rn(s0 * w00)); \
      atomicAdd(&acc[bu+1],        __float2int_rn(s0 * w10)); \
      atomicAdd(&acc[bu+KL],       __float2int_rn(s0 * w01)); \
      atomicAdd(&acc[bu+KL+1],     __float2int_rn(s0 * w11)); \
      atomicAdd(&acc[KK+bu],       __float2int_rn(s1 * w00)); \
      atomicAdd(&acc[KK+bu+1],     __float2int_rn(s1 * w10)); \
      atomicAdd(&acc[KK+bu+KL],    __float2int_rn(s1 * w01)); \
      atomicAdd(&acc[KK+bu+KL+1],  __float2int_rn(s1 * w11)); \
    }
    SPLAT(cA.x, cA.y, a.x, c.x)
    SPLAT(cA.z, cA.w, a.y, c.y)
    SPLAT(cB.x, cB.y, a.z, c.z)
    SPLAT(cB.z, cB.w, a.w, c.w)
    #undef SPLAT
  }
  __syncthreads();

  // epilogue: thread owns cells 4t..4t+3; one divide per cell, shared by pair
  int4  ia = ((const int4*)acc)[tid];
  int4  ib = ((const int4*)acc)[256 + tid];
  uint4 uw = ((const uint4*)wsl)[tid];
  float w0 = (float)uw.x * WS_INV, w1 = (float)uw.y * WS_INV;
  float w2 = (float)uw.z * WS_INV, w3 = (float)uw.w * WS_INV;
  float i0 = ACC_INV / fmaxf(w0, EPSF);
  float i1 = ACC_INV / fmaxf(w1, EPSF);
  float i2 = ACC_INV / fmaxf(w2, EPSF);
  float i3 = ACC_INV / fmaxf(w3, EPSF);
  const size_t ob = ((size_t)(b << 10) | c0) << 10;
  ((float4*)(world + ob))[tid] =
      make_float4((float)ia.x * i0, (float)ia.y * i1, (float)ia.z * i2, (float)ia.w * i3);
  ((float4*)(world + ob + KK))[tid] =
      make_float4((float)ib.x * i0, (float)ib.y * i1, (float)ib.z * i2, (float)ib.w * i3);

  // first 16 pairs of each batch also emit the broadcast weights output
  if (pr < 16)
    ((float4*)(weights_out + ((size_t)(b * 16 + pr) << 10)))[tid] =
        make_float4(w0, w1, w2, w3);
}

extern "C" void kernel_launch(void* const* d_in, const int* in_sizes, int n_in,
                              void* d_out, int out_size, void* d_ws, size_t ws_size,
                              hipStream_t stream) {
  const float*  feats = (const float*)d_in[0];   // (B,T,D,HP,WP) = (B,1024,4096)
  const float2* coord = (const float2*)d_in[1];  // (B,HP,WP) float2
  float* out = (float*)d_out;
  float* world       = out;                          // B*CC*KK
  float* weights_out = out + (size_t)BB * CC * KK;   // B*16*KK

  (void)d_ws; (void)ws_size;  // unused: no workspace, no inter-kernel state

  WLP_fused_kernel<<<BB * CC / 2, 256, 0, stream>>>(feats, coord, world, weights_out);
}